// Round 1
// baseline (1656.115 us; speedup 1.0000x reference)
//
#include <hip/hip_runtime.h>
#include <hip/hip_bf16.h>
#include <math.h>

#define NN 32
#define CC 64
#define TT 256
#define VV 25
#define PAD 68   // LDS row stride (floats): 272B, 16B-aligned, avoids 32-way conflicts

// fast tanh via exp identity: tanh(x) = sign(x) * (1 - 2e/(1+e)), e = exp(-2|x|)
__device__ __forceinline__ float fast_tanh(float x) {
  float ax = fabsf(x);
  float e = __expf(-2.0f * ax);
  float r = 1.0f - 2.0f * e / (1.0f + e);
  return copysignf(r, x);
}

// Compute one projection row (64 outputs) for this thread's t-column, writing to an LDS row.
// xs must be fully-inlined register array (all indices static after unroll).
__device__ __forceinline__ void proj_row(const float* xs, const float* Wl,
                                         const float* bl, float* dst) {
  for (int d4 = 0; d4 < 16; ++d4) {        // runtime loop: dst/Wl are LDS (ok)
    float4 r;
    #pragma unroll
    for (int j = 0; j < 4; ++j) {
      const int d = d4 * 4 + j;
      float acc = bl[d];
      #pragma unroll
      for (int c = 0; c < CC; ++c) acc += xs[c] * Wl[d * CC + c];
      ((float*)&r)[j] = acc;
    }
    *(float4*)&dst[d4 * 4] = r;
  }
}

__global__ void k0_zero(float* __restrict__ p) { p[threadIdx.x] = 0.0f; }

__global__ __launch_bounds__(256)
void k1_attn(const float* __restrict__ x,
             const float* __restrict__ Wq, const float* __restrict__ bq,
             const float* __restrict__ Wk, const float* __restrict__ bk,
             const float* __restrict__ Wv, const float* __restrict__ bv,
             float* __restrict__ stats,    // [0:64) sum, [64:128) sumsq (atomic)
             float* __restrict__ outbuf,   // ws path: [n][v][s][c]; fallback: ncsv scatter
             int to_ws)
{
  __shared__ float kl[TT * PAD];   // 69,632 B
  __shared__ float vl[TT * PAD];   // 69,632 B
  __shared__ float Wl[CC * CC];    // 16,384 B (reused as reduction buffer)
  __shared__ float bl[CC];

  const int tid = threadIdx.x;
  const int bid = blockIdx.x;
  const int n = bid / VV, v = bid - n * VV;

  // ---- this thread's x column: xs[c] = x[n, c, t=tid, v]
  float xs[CC];
  {
    const float* xp = x + ((size_t)n * CC * TT + tid) * VV + v;
    #pragma unroll
    for (int c = 0; c < CC; ++c) xs[c] = xp[(size_t)c * TT * VV];
  }

  // ---- stage Wq, compute q row into kl (temp), reload to regs with static indices
  {
    const float4* Wg = (const float4*)Wq;
    float4* Wd = (float4*)Wl;
    #pragma unroll
    for (int j = 0; j < 4; ++j) Wd[j * 256 + tid] = Wg[j * 256 + tid];
    if (tid < CC) bl[tid] = bq[tid];
    __syncthreads();
    proj_row(xs, Wl, bl, &kl[tid * PAD]);   // private row, no cross-thread use yet
  }
  float q[CC];
  #pragma unroll
  for (int c4 = 0; c4 < 16; ++c4) {
    float4 t4 = *(const float4*)&kl[tid * PAD + c4 * 4];
    q[c4 * 4 + 0] = t4.x; q[c4 * 4 + 1] = t4.y;
    q[c4 * 4 + 2] = t4.z; q[c4 * 4 + 3] = t4.w;
  }
  __syncthreads();   // everyone done with Wl(q) before restage

  // ---- stage Wk, compute k rows into kl
  {
    const float4* Wg = (const float4*)Wk;
    float4* Wd = (float4*)Wl;
    #pragma unroll
    for (int j = 0; j < 4; ++j) Wd[j * 256 + tid] = Wg[j * 256 + tid];
    if (tid < CC) bl[tid] = bk[tid];
    __syncthreads();
    proj_row(xs, Wl, bl, &kl[tid * PAD]);
    __syncthreads();   // k rows visible to all; Wl free for restage
  }
  // ---- stage Wv, compute v rows into vl
  {
    const float4* Wg = (const float4*)Wv;
    float4* Wd = (float4*)Wl;
    #pragma unroll
    for (int j = 0; j < 4; ++j) Wd[j * 256 + tid] = Wg[j * 256 + tid];
    if (tid < CC) bl[tid] = bv[tid];
    __syncthreads();
    proj_row(xs, Wl, bl, &vl[tid * PAD]);
    __syncthreads();
  }

  // ---- attention: thread s = tid owns row s of att and out
  float out[CC];
  #pragma unroll
  for (int c = 0; c < CC; ++c) out[c] = 0.0f;

  for (int t = 0; t < TT; ++t) {
    const float4* kr = (const float4*)&kl[t * PAD];
    float acc = 0.0f;
    #pragma unroll
    for (int c4 = 0; c4 < 16; ++c4) {
      float4 kk = kr[c4];
      acc += q[c4 * 4 + 0] * kk.x + q[c4 * 4 + 1] * kk.y
           + q[c4 * 4 + 2] * kk.z + q[c4 * 4 + 3] * kk.w;
    }
    float a = fast_tanh(acc * 0.125f);   // 1/sqrt(64)
    const float4* vr = (const float4*)&vl[t * PAD];
    #pragma unroll
    for (int c4 = 0; c4 < 16; ++c4) {
      float4 vv = vr[c4];
      out[c4 * 4 + 0] += a * vv.x; out[c4 * 4 + 1] += a * vv.y;
      out[c4 * 4 + 2] += a * vv.z; out[c4 * 4 + 3] += a * vv.w;
    }
  }
  __syncthreads();   // done reading kl/vl

  // ---- stage out rows into vl as out_lds[s][c] (stride PAD)
  float* out_lds = vl;
  #pragma unroll
  for (int c4 = 0; c4 < 16; ++c4) {
    float4 r = make_float4(out[c4 * 4 + 0], out[c4 * 4 + 1],
                           out[c4 * 4 + 2], out[c4 * 4 + 3]);
    *(float4*)&out_lds[tid * PAD + c4 * 4] = r;
  }
  __syncthreads();

  // ---- per-channel partial sums over s (for LayerNorm), then global atomics
  {
    const int c = tid & 63, g = tid >> 6;
    float s1 = 0.0f, s2 = 0.0f;
    for (int s = g * 64; s < g * 64 + 64; ++s) {
      float val = out_lds[s * PAD + c];
      s1 += val; s2 += val * val;
    }
    float* part = Wl;   // reuse: [0:256) sums, [256:512) sumsq
    part[tid] = s1;
    part[256 + tid] = s2;
    __syncthreads();
    if (tid < 64) {
      float a1 = part[tid] + part[64 + tid] + part[128 + tid] + part[192 + tid];
      float a2 = part[256 + tid] + part[320 + tid] + part[384 + tid] + part[448 + tid];
      atomicAdd(&stats[tid], a1);
      atomicAdd(&stats[64 + tid], a2);
    }
  }

  // ---- emit pre-LN output
  if (to_ws) {
    // contiguous [n][v][s][c] block: fully coalesced float4 stores
    float4* ob = (float4*)(outbuf + (size_t)(n * VV + v) * (TT * CC));
    #pragma unroll
    for (int k2 = 0; k2 < 16; ++k2) {
      int idx = k2 * 256 + tid;
      int s = idx >> 4, cq = idx & 15;
      ob[idx] = *(const float4*)&out_lds[s * PAD + cq * 4];
    }
  } else {
    // fallback: scatter directly into ncsv layout
    float* ob = outbuf + (size_t)n * CC * TT * VV + v;
    for (int e = tid; e < TT * CC; e += 256) {
      int s = e >> 6, c = e & 63;
      ob[(size_t)c * TT * VV + (size_t)s * VV] = out_lds[s * PAD + c];
    }
  }
}

__global__ void k2_stats(const float* __restrict__ stats,
                         const float* __restrict__ gamma,
                         const float* __restrict__ beta,
                         float* __restrict__ ss)   // [0:64) scale, [64:128) shift
{
  int c = threadIdx.x;
  if (c < 64) {
    const float M = (float)(NN * TT * VV);
    float mean = stats[c] / M;
    float var = stats[64 + c] / M - mean * mean;
    float sc = gamma[c] * rsqrtf(var + 1e-5f);
    ss[c] = sc;
    ss[64 + c] = beta[c] - mean * sc;
  }
}

// Transpose [n][v][s][c] -> [n][c][s][v] with LN applied; coalesced both sides.
__global__ __launch_bounds__(256)
void k3_emit(const float* __restrict__ ob, const float* __restrict__ ss,
             float* __restrict__ out)
{
  __shared__ float tile[VV * 8 * 65];   // [v][sL][c], c-row padded to 65
  __shared__ float scl[64], sft[64];
  const int bid = blockIdx.x;
  const int n = bid >> 5, sb = bid & 31;   // 32 s-blocks of 8
  const int tid = threadIdx.x;
  if (tid < 64) { scl[tid] = ss[tid]; sft[tid] = ss[64 + tid]; }
  for (int v = 0; v < VV; ++v) {
    const float2* src = (const float2*)(ob + (((size_t)(n * VV + v)) * TT + sb * 8) * CC);
    float2 f = src[tid];
    int e = tid * 2; int sL = e >> 6, c = e & 63;
    tile[(v * 8 + sL) * 65 + c] = f.x;
    tile[(v * 8 + sL) * 65 + c + 1] = f.y;
  }
  __syncthreads();
  float* outn = out + (size_t)n * CC * TT * VV + sb * 8 * VV;
  for (int e = tid; e < CC * 200; e += 256) {
    int c = e / 200, r = e - c * 200;
    int sL = r / 25, v = r - sL * 25;
    float val = tile[(v * 8 + sL) * 65 + c];
    outn[(size_t)c * TT * VV + sL * VV + v] = val * scl[c] + sft[c];
  }
}

// Fallback: in-place LN over ncsv output
__global__ void k3b_inplace(float* __restrict__ out, const float* __restrict__ ss) {
  __shared__ float scl[64], sft[64];
  if (threadIdx.x < 64) { scl[threadIdx.x] = ss[threadIdx.x]; sft[threadIdx.x] = ss[64 + threadIdx.x]; }
  __syncthreads();
  const size_t total = (size_t)NN * CC * TT * VV;
  size_t i = ((size_t)blockIdx.x * 256 + threadIdx.x) * 4;
  const size_t stride = (size_t)gridDim.x * 256 * 4;
  for (; i < total; i += stride) {
    float4 val = *(float4*)(out + i);
    int c = (int)((i / (TT * VV)) & 63);
    val.x = val.x * scl[c] + sft[c];
    val.y = val.y * scl[c] + sft[c];
    val.z = val.z * scl[c] + sft[c];
    val.w = val.w * scl[c] + sft[c];
    *(float4*)(out + i) = val;
  }
}

extern "C" void kernel_launch(void* const* d_in, const int* in_sizes, int n_in,
                              void* d_out, int out_size, void* d_ws, size_t ws_size,
                              hipStream_t stream) {
  (void)in_sizes; (void)n_in; (void)out_size;
  const float* x     = (const float*)d_in[0];
  const float* Wq    = (const float*)d_in[1];
  const float* bq    = (const float*)d_in[2];
  const float* Wk    = (const float*)d_in[3];
  const float* bk    = (const float*)d_in[4];
  const float* Wv    = (const float*)d_in[5];
  const float* bv    = (const float*)d_in[6];
  const float* gamma = (const float*)d_in[7];
  const float* beta  = (const float*)d_in[8];
  float* out = (float*)d_out;
  float* wsf = (float*)d_ws;

  float* stats = wsf;         // 128 floats
  float* ss    = wsf + 128;   // 128 floats
  float* ob    = wsf + 256;   // pre-LN buffer, [n][v][s][c]
  const size_t need = 1024 + (size_t)NN * VV * TT * CC * sizeof(float);
  const bool use_ws = ws_size >= need;

  k0_zero<<<1, 128, 0, stream>>>(stats);
  k1_attn<<<NN * VV, 256, 0, stream>>>(x, Wq, bq, Wk, bk, Wv, bv,
                                       stats, use_ws ? ob : out, use_ws ? 1 : 0);
  k2_stats<<<1, 64, 0, stream>>>(stats, gamma, beta, ss);
  if (use_ws) {
    k3_emit<<<NN * 32, 256, 0, stream>>>(ob, ss, out);
  } else {
    k3b_inplace<<<2048, 256, 0, stream>>>(out, ss);
  }
}

// Round 3
// 1073.890 us; speedup vs baseline: 1.5422x; 1.5422x over previous
//
#include <hip/hip_runtime.h>
#include <hip/hip_bf16.h>
#include <math.h>

#define NN 32
#define CC 64
#define TT 256
#define VV 25
#define PAD 68   // LDS row stride for old fused path
#define KVT 32   // K/V tile rows in streaming attention

// fast tanh via exp identity: tanh(x) = sign(x) * (1 - 2e/(1+e)), e = exp(-2|x|)
__device__ __forceinline__ float fast_tanh(float x) {
  float ax = fabsf(x);
  float e = __expf(-2.0f * ax);
  float r = 1.0f - 2.0f * e / (1.0f + e);
  return copysignf(r, x);
}

__global__ void k0_zero(float* __restrict__ p) { p[threadIdx.x] = 0.0f; }

// ============================================================================
// Path A/B: split pipeline
// ============================================================================

// One projection: 64 outputs for this thread's x-column. W reads are
// wave-uniform (scalar-load eligible); xs statically indexed (c4 fully unrolled).
__device__ __forceinline__ void proj_one(const float* xs, const float* __restrict__ W,
                                         const float* __restrict__ b, float* dst) {
  for (int db = 0; db < 8; ++db) {          // runtime loop: W/b/dst are memory
    float acc[8];
    #pragma unroll
    for (int j = 0; j < 8; ++j) acc[j] = b[db * 8 + j];
    #pragma unroll
    for (int c4 = 0; c4 < 16; ++c4) {
      #pragma unroll
      for (int j = 0; j < 8; ++j) {
        float4 w = *(const float4*)&W[(db * 8 + j) * 64 + c4 * 4];
        acc[j] = fmaf(w.x, xs[c4 * 4 + 0], acc[j]);
        acc[j] = fmaf(w.y, xs[c4 * 4 + 1], acc[j]);
        acc[j] = fmaf(w.z, xs[c4 * 4 + 2], acc[j]);
        acc[j] = fmaf(w.w, xs[c4 * 4 + 3], acc[j]);
      }
    }
    *(float4*)(dst + db * 8)     = make_float4(acc[0], acc[1], acc[2], acc[3]);
    *(float4*)(dst + db * 8 + 4) = make_float4(acc[4], acc[5], acc[6], acc[7]);
  }
}

// QKV projection: thread = one (t,v) column of one n. x reads coalesced across
// lanes; outputs [n][v][t][c] rows (256 B contiguous per thread).
__global__ __launch_bounds__(256)
void k_proj(const float* __restrict__ x,
            const float* __restrict__ Wq, const float* __restrict__ bq,
            const float* __restrict__ Wk, const float* __restrict__ bk,
            const float* __restrict__ Wv, const float* __restrict__ bv,
            float* __restrict__ qb, float* __restrict__ kb, float* __restrict__ vb)
{
  const int tid = threadIdx.x;
  const int n = blockIdx.x / 25;
  const int tvb = blockIdx.x - n * 25;
  const int tv = tvb * 256 + tid;           // 0..6399, = t*25+v
  float xs[CC];
  {
    const float* xp = x + (size_t)n * CC * TT * VV + tv;
    #pragma unroll
    for (int c = 0; c < CC; ++c) xs[c] = xp[c * (TT * VV)];
  }
  const int t = tv / 25, v = tv - 25 * (tv / 25);
  const size_t obase = (((size_t)(n * VV + v)) * TT + t) * CC;
  proj_one(xs, Wq, bq, qb + obase);
  proj_one(xs, Wk, bk, kb + obase);
  proj_one(xs, Wv, bv, vb + obase);
}

// Streaming attention: block = one (n,v); thread t = q-row t.
// K/V in 32-row double-buffered LDS tiles, reg-staged (loads issued after the
// barrier, ds_write after compute so HBM/L3 latency hides under the FMAs).
__global__ __launch_bounds__(256, 3)
void k_attn(const float* __restrict__ qb, const float* __restrict__ kb,
            const float* __restrict__ vb, float* __restrict__ stats,
            float* __restrict__ obuf, int modeA)
{
  __shared__ float kt[2][KVT * CC];   // 8 KB each
  __shared__ float vt[2][KVT * CC];
  __shared__ float red1[256], red2[256];

  const int tid = threadIdx.x;
  const int bid = blockIdx.x;                 // n*25+v
  const size_t base = (size_t)bid * (TT * CC);

  float q[CC];
  {
    const float4* qp = (const float4*)(qb + base + (size_t)tid * CC);
    #pragma unroll
    for (int i = 0; i < 16; ++i) {
      float4 f = qp[i];
      q[i * 4 + 0] = f.x; q[i * 4 + 1] = f.y; q[i * 4 + 2] = f.z; q[i * 4 + 3] = f.w;
    }
  }
  float out[CC];
  #pragma unroll
  for (int c = 0; c < CC; ++c) out[c] = 0.0f;

  // prologue: stage tile 0 (reg->LDS)
  {
    const float4* ks = (const float4*)(kb + base);
    const float4* vs = (const float4*)(vb + base);
    float4 a0 = ks[tid], a1 = ks[256 + tid];
    float4 b0 = vs[tid], b1 = vs[256 + tid];
    float4* kd = (float4*)kt[0]; float4* vd = (float4*)vt[0];
    kd[tid] = a0; kd[256 + tid] = a1;
    vd[tid] = b0; vd[256 + tid] = b1;
  }

  int cur = 0;
  for (int tile = 0; tile < TT / KVT; ++tile) {
    __syncthreads();                        // buf[cur] ready for all waves
    float4 ks0, ks1, vs0, vs1;
    const bool more = (tile < TT / KVT - 1);
    if (more) {                             // issue next-tile loads (in flight)
      const float4* ks = (const float4*)(kb + base + (size_t)(tile + 1) * KVT * CC);
      const float4* vs = (const float4*)(vb + base + (size_t)(tile + 1) * KVT * CC);
      ks0 = ks[tid]; ks1 = ks[256 + tid];
      vs0 = vs[tid]; vs1 = vs[256 + tid];
    }
    const float* ktc = kt[cur];
    const float* vtc = vt[cur];
    #pragma unroll 4
    for (int tt = 0; tt < KVT; ++tt) {
      const float4* kr = (const float4*)&ktc[tt * CC];
      const float4* vr = (const float4*)&vtc[tt * CC];
      float a0 = 0.f, a1 = 0.f, a2 = 0.f, a3 = 0.f;   // 4 partial dot chains
      #pragma unroll
      for (int c4 = 0; c4 < 16; ++c4) {
        float4 kk = kr[c4];
        a0 = fmaf(q[c4 * 4 + 0], kk.x, a0);
        a1 = fmaf(q[c4 * 4 + 1], kk.y, a1);
        a2 = fmaf(q[c4 * 4 + 2], kk.z, a2);
        a3 = fmaf(q[c4 * 4 + 3], kk.w, a3);
      }
      float a = fast_tanh(((a0 + a1) + (a2 + a3)) * 0.125f);
      #pragma unroll
      for (int c4 = 0; c4 < 16; ++c4) {
        float4 vv = vr[c4];
        out[c4 * 4 + 0] = fmaf(a, vv.x, out[c4 * 4 + 0]);
        out[c4 * 4 + 1] = fmaf(a, vv.y, out[c4 * 4 + 1]);
        out[c4 * 4 + 2] = fmaf(a, vv.z, out[c4 * 4 + 2]);
        out[c4 * 4 + 3] = fmaf(a, vv.w, out[c4 * 4 + 3]);
      }
    }
    if (more) {                             // write-late: latency already hidden
      float4* kd = (float4*)kt[cur ^ 1]; float4* vd = (float4*)vt[cur ^ 1];
      kd[tid] = ks0; kd[256 + tid] = ks1;
      vd[tid] = vs0; vd[256 + tid] = vs1;
    }
    cur ^= 1;
  }

  // LN partial sums: per-channel butterfly across the wave, then cross-wave.
  const int lane = tid & 63, wid = tid >> 6;
  #pragma unroll
  for (int c = 0; c < CC; ++c) {
    float v1 = out[c];
    float v2 = v1 * v1;
    #pragma unroll
    for (int m = 32; m >= 1; m >>= 1) {
      v1 += __shfl_xor(v1, m, 64);
      v2 += __shfl_xor(v2, m, 64);
    }
    if (lane == c) { red1[wid * 64 + c] = v1; red2[wid * 64 + c] = v2; }
  }
  __syncthreads();
  if (tid < 64) {
    float s1 = red1[tid] + red1[64 + tid] + red1[128 + tid] + red1[192 + tid];
    float s2 = red2[tid] + red2[64 + tid] + red2[128 + tid] + red2[192 + tid];
    atomicAdd(&stats[tid], s1);
    atomicAdd(&stats[64 + tid], s2);
  }

  // emit pre-LN
  if (modeA) {
    float4* op = (float4*)(obuf + base + (size_t)tid * CC);
    #pragma unroll
    for (int i = 0; i < 16; ++i)
      op[i] = make_float4(out[i * 4], out[i * 4 + 1], out[i * 4 + 2], out[i * 4 + 3]);
  } else {
    const int n = bid / VV, v = bid - n * VV;
    float* op = obuf + (size_t)n * CC * TT * VV + (size_t)tid * VV + v;
    #pragma unroll
    for (int c = 0; c < CC; ++c) op[(size_t)c * TT * VV] = out[c];
  }
}

// ============================================================================
// Shared epilogue kernels (unchanged from round 1, verified passing)
// ============================================================================

__global__ void k2_stats(const float* __restrict__ stats,
                         const float* __restrict__ gamma,
                         const float* __restrict__ beta,
                         float* __restrict__ ss)
{
  int c = threadIdx.x;
  if (c < 64) {
    const float M = (float)(NN * TT * VV);
    float mean = stats[c] / M;
    float var = stats[64 + c] / M - mean * mean;
    float sc = gamma[c] * rsqrtf(var + 1e-5f);
    ss[c] = sc;
    ss[64 + c] = beta[c] - mean * sc;
  }
}

__global__ __launch_bounds__(256)
void k3_emit(const float* __restrict__ ob, const float* __restrict__ ss,
             float* __restrict__ out)
{
  __shared__ float tile[VV * 8 * 65];
  __shared__ float scl[64], sft[64];
  const int bid = blockIdx.x;
  const int n = bid >> 5, sb = bid & 31;
  const int tid = threadIdx.x;
  if (tid < 64) { scl[tid] = ss[tid]; sft[tid] = ss[64 + tid]; }
  for (int v = 0; v < VV; ++v) {
    const float2* src = (const float2*)(ob + (((size_t)(n * VV + v)) * TT + sb * 8) * CC);
    float2 f = src[tid];
    int e = tid * 2; int sL = e >> 6, c = e & 63;
    tile[(v * 8 + sL) * 65 + c] = f.x;
    tile[(v * 8 + sL) * 65 + c + 1] = f.y;
  }
  __syncthreads();
  float* outn = out + (size_t)n * CC * TT * VV + sb * 8 * VV;
  for (int e = tid; e < CC * 200; e += 256) {
    int c = e / 200, r = e - c * 200;
    int sL = r / 25, v = r - sL * 25;
    float val = tile[(v * 8 + sL) * 65 + c];
    outn[(size_t)c * TT * VV + sL * VV + v] = val * scl[c] + sft[c];
  }
}

__global__ void k3b_inplace(float* __restrict__ out, const float* __restrict__ ss) {
  __shared__ float scl[64], sft[64];
  if (threadIdx.x < 64) { scl[threadIdx.x] = ss[threadIdx.x]; sft[threadIdx.x] = ss[64 + threadIdx.x]; }
  __syncthreads();
  const size_t total = (size_t)NN * CC * TT * VV;
  size_t i = ((size_t)blockIdx.x * 256 + threadIdx.x) * 4;
  const size_t stride = (size_t)gridDim.x * 256 * 4;
  for (; i < total; i += stride) {
    float4 val = *(float4*)(out + i);
    int c = (int)((i / (TT * VV)) & 63);
    val.x = val.x * scl[c] + sft[c];
    val.y = val.y * scl[c] + sft[c];
    val.z = val.z * scl[c] + sft[c];
    val.w = val.w * scl[c] + sft[c];
    *(float4*)(out + i) = val;
  }
}

// ============================================================================
// Path C fallback: round-1 fused kernel (verbatim, known-correct)
// ============================================================================

__device__ __forceinline__ void proj_row(const float* xs, const float* Wl,
                                         const float* bl, float* dst) {
  for (int d4 = 0; d4 < 16; ++d4) {
    float4 r;
    #pragma unroll
    for (int j = 0; j < 4; ++j) {
      const int d = d4 * 4 + j;
      float acc = bl[d];
      #pragma unroll
      for (int c = 0; c < CC; ++c) acc += xs[c] * Wl[d * CC + c];
      ((float*)&r)[j] = acc;
    }
    *(float4*)&dst[d4 * 4] = r;
  }
}

__global__ __launch_bounds__(256)
void k1_attn(const float* __restrict__ x,
             const float* __restrict__ Wq, const float* __restrict__ bq,
             const float* __restrict__ Wk, const float* __restrict__ bk,
             const float* __restrict__ Wv, const float* __restrict__ bv,
             float* __restrict__ stats, float* __restrict__ outbuf, int to_ws)
{
  __shared__ float kl[TT * PAD];
  __shared__ float vl[TT * PAD];
  __shared__ float Wl[CC * CC];
  __shared__ float bl[CC];
  const int tid = threadIdx.x;
  const int bid = blockIdx.x;
  const int n = bid / VV, v = bid - n * VV;
  float xs[CC];
  {
    const float* xp = x + ((size_t)n * CC * TT + tid) * VV + v;
    #pragma unroll
    for (int c = 0; c < CC; ++c) xs[c] = xp[(size_t)c * TT * VV];
  }
  {
    const float4* Wg = (const float4*)Wq;
    float4* Wd = (float4*)Wl;
    #pragma unroll
    for (int j = 0; j < 4; ++j) Wd[j * 256 + tid] = Wg[j * 256 + tid];
    if (tid < CC) bl[tid] = bq[tid];
    __syncthreads();
    proj_row(xs, Wl, bl, &kl[tid * PAD]);
  }
  float q[CC];
  #pragma unroll
  for (int c4 = 0; c4 < 16; ++c4) {
    float4 t4 = *(const float4*)&kl[tid * PAD + c4 * 4];
    q[c4 * 4 + 0] = t4.x; q[c4 * 4 + 1] = t4.y;
    q[c4 * 4 + 2] = t4.z; q[c4 * 4 + 3] = t4.w;
  }
  __syncthreads();
  {
    const float4* Wg = (const float4*)Wk;
    float4* Wd = (float4*)Wl;
    #pragma unroll
    for (int j = 0; j < 4; ++j) Wd[j * 256 + tid] = Wg[j * 256 + tid];
    if (tid < CC) bl[tid] = bk[tid];
    __syncthreads();
    proj_row(xs, Wl, bl, &kl[tid * PAD]);
    __syncthreads();
  }
  {
    const float4* Wg = (const float4*)Wv;
    float4* Wd = (float4*)Wl;
    #pragma unroll
    for (int j = 0; j < 4; ++j) Wd[j * 256 + tid] = Wg[j * 256 + tid];
    if (tid < CC) bl[tid] = bv[tid];
    __syncthreads();
    proj_row(xs, Wl, bl, &vl[tid * PAD]);
    __syncthreads();
  }
  float out[CC];
  #pragma unroll
  for (int c = 0; c < CC; ++c) out[c] = 0.0f;
  for (int t = 0; t < TT; ++t) {
    const float4* kr = (const float4*)&kl[t * PAD];
    float acc = 0.0f;
    #pragma unroll
    for (int c4 = 0; c4 < 16; ++c4) {
      float4 kk = kr[c4];
      acc += q[c4 * 4 + 0] * kk.x + q[c4 * 4 + 1] * kk.y
           + q[c4 * 4 + 2] * kk.z + q[c4 * 4 + 3] * kk.w;
    }
    float a = fast_tanh(acc * 0.125f);
    const float4* vr = (const float4*)&vl[t * PAD];
    #pragma unroll
    for (int c4 = 0; c4 < 16; ++c4) {
      float4 vv = vr[c4];
      out[c4 * 4 + 0] += a * vv.x; out[c4 * 4 + 1] += a * vv.y;
      out[c4 * 4 + 2] += a * vv.z; out[c4 * 4 + 3] += a * vv.w;
    }
  }
  __syncthreads();
  float* out_lds = vl;
  #pragma unroll
  for (int c4 = 0; c4 < 16; ++c4) {
    *(float4*)&out_lds[tid * PAD + c4 * 4] =
        make_float4(out[c4 * 4 + 0], out[c4 * 4 + 1], out[c4 * 4 + 2], out[c4 * 4 + 3]);
  }
  __syncthreads();
  {
    const int c = tid & 63, g = tid >> 6;
    float s1 = 0.0f, s2 = 0.0f;
    for (int s = g * 64; s < g * 64 + 64; ++s) {
      float val = out_lds[s * PAD + c];
      s1 += val; s2 += val * val;
    }
    float* part = Wl;
    part[tid] = s1;
    part[256 + tid] = s2;
    __syncthreads();
    if (tid < 64) {
      float a1 = part[tid] + part[64 + tid] + part[128 + tid] + part[192 + tid];
      float a2 = part[256 + tid] + part[320 + tid] + part[384 + tid] + part[448 + tid];
      atomicAdd(&stats[tid], a1);
      atomicAdd(&stats[64 + tid], a2);
    }
  }
  if (to_ws) {
    float4* ob = (float4*)(outbuf + (size_t)(n * VV + v) * (TT * CC));
    #pragma unroll
    for (int k2 = 0; k2 < 16; ++k2) {
      int idx = k2 * 256 + tid;
      int s = idx >> 4, cq = idx & 15;
      ob[idx] = *(const float4*)&out_lds[s * PAD + cq * 4];
    }
  } else {
    float* ob = outbuf + (size_t)n * CC * TT * VV + v;
    for (int e = tid; e < TT * CC; e += 256) {
      int s = e >> 6, c = e & 63;
      ob[(size_t)c * TT * VV + (size_t)s * VV] = out_lds[s * PAD + c];
    }
  }
}

// ============================================================================

extern "C" void kernel_launch(void* const* d_in, const int* in_sizes, int n_in,
                              void* d_out, int out_size, void* d_ws, size_t ws_size,
                              hipStream_t stream) {
  (void)in_sizes; (void)n_in; (void)out_size;
  const float* x     = (const float*)d_in[0];
  const float* Wq    = (const float*)d_in[1];
  const float* bq    = (const float*)d_in[2];
  const float* Wk    = (const float*)d_in[3];
  const float* bk    = (const float*)d_in[4];
  const float* Wv    = (const float*)d_in[5];
  const float* bv    = (const float*)d_in[6];
  const float* gamma = (const float*)d_in[7];
  const float* beta  = (const float*)d_in[8];
  float* out = (float*)d_out;
  float* wsf = (float*)d_ws;

  float* stats = wsf;
  float* ss    = wsf + 128;
  const size_t per = (size_t)NN * VV * TT * CC;              // floats per buffer
  const size_t needB = 1024 + 3 * per * sizeof(float);       // ~157 MB
  const size_t needA = needB + per * sizeof(float);          // ~210 MB

  k0_zero<<<1, 128, 0, stream>>>(stats);

  if (ws_size >= needB) {
    float* qb = wsf + 256;
    float* kb = qb + per;
    float* vb = kb + per;
    const bool A = ws_size >= needA;
    float* ob = vb + per;
    k_proj<<<NN * 25, 256, 0, stream>>>(x, Wq, bq, Wk, bk, Wv, bv, qb, kb, vb);
    k_attn<<<NN * VV, 256, 0, stream>>>(qb, kb, vb, stats, A ? ob : out, A ? 1 : 0);
    k2_stats<<<1, 64, 0, stream>>>(stats, gamma, beta, ss);
    if (A) k3_emit<<<NN * 32, 256, 0, stream>>>(ob, ss, out);
    else   k3b_inplace<<<2048, 256, 0, stream>>>(out, ss);
  } else {
    float* ob = wsf + 256;
    const size_t needC = 1024 + per * sizeof(float);
    const bool useC = ws_size >= needC;
    k1_attn<<<NN * VV, 256, 0, stream>>>(x, Wq, bq, Wk, bk, Wv, bv,
                                         stats, useC ? ob : out, useC ? 1 : 0);
    k2_stats<<<1, 64, 0, stream>>>(stats, gamma, beta, ss);
    if (useC) k3_emit<<<NN * 32, 256, 0, stream>>>(ob, ss, out);
    else      k3b_inplace<<<2048, 256, 0, stream>>>(out, ss);
  }
}

// Round 4
// 575.835 us; speedup vs baseline: 2.8760x; 1.8649x over previous
//
#include <hip/hip_runtime.h>
#include <hip/hip_bf16.h>
#include <math.h>

#define NN 32
#define CC 64
#define TT 256
#define VV 25
#define PAD 68   // LDS row stride for old vector paths
#define KVT 32   // K/V tile rows in streaming attention

// LDS strides (in shorts) for MFMA kernel: chosen so b128 ops are 16B-aligned
// and frag reads land on distinct banks (72*2=144B, 40*2=80B; both %16==0).
#define KST 72
#define VST 40
#define PST 40

typedef __attribute__((ext_vector_type(8))) short bf16x8;
typedef __attribute__((ext_vector_type(4))) float f32x4;

// fast tanh via exp identity: tanh(x) = sign(x) * (1 - 2e/(1+e)), e = exp(-2|x|)
__device__ __forceinline__ float fast_tanh(float x) {
  float ax = fabsf(x);
  float e = __expf(-2.0f * ax);
  float r = 1.0f - 2.0f * e / (1.0f + e);
  return copysignf(r, x);
}

__device__ __forceinline__ unsigned short f2bf(float f) {   // RTN-even fp32->bf16
  unsigned u = __float_as_uint(f);
  u += 0x7fff + ((u >> 16) & 1u);
  return (unsigned short)(u >> 16);
}
__device__ __forceinline__ float bf2f(unsigned short h) {
  return __uint_as_float(((unsigned)h) << 16);
}
// 8 fp32 -> bf16 hi + residual lo (2-term split, ~2^-18 relative accuracy)
__device__ __forceinline__ void cvt8(float4 a, float4 b, bf16x8& h8, bf16x8& l8) {
  unsigned short h;
  h = f2bf(a.x); h8[0] = (short)h; l8[0] = (short)f2bf(a.x - bf2f(h));
  h = f2bf(a.y); h8[1] = (short)h; l8[1] = (short)f2bf(a.y - bf2f(h));
  h = f2bf(a.z); h8[2] = (short)h; l8[2] = (short)f2bf(a.z - bf2f(h));
  h = f2bf(a.w); h8[3] = (short)h; l8[3] = (short)f2bf(a.w - bf2f(h));
  h = f2bf(b.x); h8[4] = (short)h; l8[4] = (short)f2bf(b.x - bf2f(h));
  h = f2bf(b.y); h8[5] = (short)h; l8[5] = (short)f2bf(b.y - bf2f(h));
  h = f2bf(b.z); h8[6] = (short)h; l8[6] = (short)f2bf(b.z - bf2f(h));
  h = f2bf(b.w); h8[7] = (short)h; l8[7] = (short)f2bf(b.w - bf2f(h));
}

__global__ void k0_zero(float* __restrict__ p) { p[threadIdx.x] = 0.0f; }

// ============================================================================
// QKV projection (unchanged from R3; profile next round)
// ============================================================================
__device__ __forceinline__ void proj_one(const float* xs, const float* __restrict__ W,
                                         const float* __restrict__ b, float* dst) {
  for (int db = 0; db < 8; ++db) {
    float acc[8];
    #pragma unroll
    for (int j = 0; j < 8; ++j) acc[j] = b[db * 8 + j];
    #pragma unroll
    for (int c4 = 0; c4 < 16; ++c4) {
      #pragma unroll
      for (int j = 0; j < 8; ++j) {
        float4 w = *(const float4*)&W[(db * 8 + j) * 64 + c4 * 4];
        acc[j] = fmaf(w.x, xs[c4 * 4 + 0], acc[j]);
        acc[j] = fmaf(w.y, xs[c4 * 4 + 1], acc[j]);
        acc[j] = fmaf(w.z, xs[c4 * 4 + 2], acc[j]);
        acc[j] = fmaf(w.w, xs[c4 * 4 + 3], acc[j]);
      }
    }
    *(float4*)(dst + db * 8)     = make_float4(acc[0], acc[1], acc[2], acc[3]);
    *(float4*)(dst + db * 8 + 4) = make_float4(acc[4], acc[5], acc[6], acc[7]);
  }
}

__global__ __launch_bounds__(256)
void k_proj(const float* __restrict__ x,
            const float* __restrict__ Wq, const float* __restrict__ bq,
            const float* __restrict__ Wk, const float* __restrict__ bk,
            const float* __restrict__ Wv, const float* __restrict__ bv,
            float* __restrict__ qb, float* __restrict__ kb, float* __restrict__ vb)
{
  const int tid = threadIdx.x;
  const int n = blockIdx.x / 25;
  const int tvb = blockIdx.x - n * 25;
  const int tv = tvb * 256 + tid;
  float xs[CC];
  {
    const float* xp = x + (size_t)n * CC * TT * VV + tv;
    #pragma unroll
    for (int c = 0; c < CC; ++c) xs[c] = xp[c * (TT * VV)];
  }
  const int t = tv / 25, v = tv - 25 * (tv / 25);
  const size_t obase = (((size_t)(n * VV + v)) * TT + t) * CC;
  proj_one(xs, Wq, bq, qb + obase);
  proj_one(xs, Wk, bk, kb + obase);
  proj_one(xs, Wv, bv, vb + obase);
}

// ============================================================================
// MFMA attention: block = one (n,v); 4 waves; wave owns 64 q-rows.
// S = Q.K^T via mfma_f32_16x16x32_bf16 (hi/lo split, 3 combos);
// tanh; P bounced through per-wave LDS; O^T = V^T.P^T (all b128 frag reads).
// ============================================================================
__global__ __launch_bounds__(256, 2)
void k_attn_mfma(const float* __restrict__ qb, const float* __restrict__ kb,
                 const float* __restrict__ vb, float* __restrict__ stats,
                 float* __restrict__ ob)
{
  __shared__ short KhL[2][32 * KST], KlL[2][32 * KST];  // [t-row][c] row-major
  __shared__ short VhL[2][64 * VST], VlL[2][64 * VST];  // [c][t]    transposed
  __shared__ short Pwh[4][64 * PST], Pwl[4][64 * PST];  // per-wave [row][t]
  __shared__ float red1[256], red2[256];

  const int tid  = threadIdx.x;
  const int lane = tid & 63;
  const int wid  = tid >> 6;
  const int l15  = lane & 15;
  const int g    = lane >> 4;          // 0..3
  const int band = wid * 64;           // wave's q-row band
  const size_t base = (size_t)blockIdx.x * (TT * CC);

  // staging coords: thread loads 8 consecutive c of one tile row
  const int sr = tid >> 3;             // 0..31 tile row
  const int sc = (tid & 7) * 8;        // c offset

  // ---- Q fragments in registers: A-layout row=l15, k=8g+e
  bf16x8 qh[4][2], ql[4][2];
  #pragma unroll
  for (int rt = 0; rt < 4; ++rt) {
    #pragma unroll
    for (int ks = 0; ks < 2; ++ks) {
      const float* p = qb + base + (size_t)(band + rt * 16 + l15) * 64 + ks * 32 + g * 8;
      cvt8(*(const float4*)p, *(const float4*)(p + 4), qh[rt][ks], ql[rt][ks]);
    }
  }

  f32x4 acc[4][4];   // [c-tile][s-tile] of O^T
  #pragma unroll
  for (int i = 0; i < 4; ++i)
    #pragma unroll
    for (int j = 0; j < 4; ++j)
      acc[i][j] = (f32x4){0.f, 0.f, 0.f, 0.f};

  // ---- prologue: stage tile 0 into buffer 0
  {
    const float* kp = kb + base + (size_t)sr * 64 + sc;
    const float* vp = vb + base + (size_t)sr * 64 + sc;
    float4 ka = *(const float4*)kp, kb4 = *(const float4*)(kp + 4);
    float4 va = *(const float4*)vp, vb4 = *(const float4*)(vp + 4);
    bf16x8 h8, l8;
    cvt8(ka, kb4, h8, l8);
    *(bf16x8*)&KhL[0][sr * KST + sc] = h8;
    *(bf16x8*)&KlL[0][sr * KST + sc] = l8;
    cvt8(va, vb4, h8, l8);
    #pragma unroll
    for (int j = 0; j < 8; ++j) {
      VhL[0][(sc + j) * VST + sr] = h8[j];
      VlL[0][(sc + j) * VST + sr] = l8[j];
    }
  }

  int cur = 0;
  for (int tl = 0; tl < 8; ++tl) {
    __syncthreads();                       // buf[cur] ready for all waves
    const bool more = (tl < 7);
    float4 ka, kb4, va, vb4;
    if (more) {                            // issue next-tile loads early
      const float* kp = kb + base + (size_t)((tl + 1) * 32 + sr) * 64 + sc;
      const float* vp = vb + base + (size_t)((tl + 1) * 32 + sr) * 64 + sc;
      ka = *(const float4*)kp; kb4 = *(const float4*)(kp + 4);
      va = *(const float4*)vp; vb4 = *(const float4*)(vp + 4);
    }

    // ---- S phase: K B-frags (col=l15 -> K row ct*16+l15, k=c)
    bf16x8 kfh[2][2], kfl[2][2];
    #pragma unroll
    for (int ct = 0; ct < 2; ++ct)
      #pragma unroll
      for (int ks = 0; ks < 2; ++ks) {
        kfh[ct][ks] = *(const bf16x8*)&KhL[cur][(ct * 16 + l15) * KST + ks * 32 + g * 8];
        kfl[ct][ks] = *(const bf16x8*)&KlL[cur][(ct * 16 + l15) * KST + ks * 32 + g * 8];
      }
    #pragma unroll
    for (int rt = 0; rt < 4; ++rt) {
      #pragma unroll
      for (int ct = 0; ct < 2; ++ct) {
        f32x4 s = (f32x4){0.f, 0.f, 0.f, 0.f};
        #pragma unroll
        for (int ks = 0; ks < 2; ++ks) {
          s = __builtin_amdgcn_mfma_f32_16x16x32_bf16(qh[rt][ks], kfh[ct][ks], s, 0, 0, 0);
          s = __builtin_amdgcn_mfma_f32_16x16x32_bf16(qh[rt][ks], kfl[ct][ks], s, 0, 0, 0);
          s = __builtin_amdgcn_mfma_f32_16x16x32_bf16(ql[rt][ks], kfh[ct][ks], s, 0, 0, 0);
        }
        // tanh + split + P write (D-layout: row=rt*16+4g+reg, col=ct*16+l15)
        #pragma unroll
        for (int r = 0; r < 4; ++r) {
          float p = fast_tanh(s[r] * 0.125f);
          unsigned short h = f2bf(p);
          int row = rt * 16 + 4 * g + r;
          Pwh[wid][row * PST + ct * 16 + l15] = (short)h;
          Pwl[wid][row * PST + ct * 16 + l15] = (short)f2bf(p - bf2f(h));
        }
      }
    }

    // ---- PV phase: O^T += V^T . P^T   (A=V^T from VhL, B=P^T from Pw)
    bf16x8 vfh[4], vfl[4], pfh[4], pfl[4];
    #pragma unroll
    for (int i = 0; i < 4; ++i) {
      vfh[i] = *(const bf16x8*)&VhL[cur][(i * 16 + l15) * VST + g * 8];
      vfl[i] = *(const bf16x8*)&VlL[cur][(i * 16 + l15) * VST + g * 8];
      pfh[i] = *(const bf16x8*)&Pwh[wid][(i * 16 + l15) * PST + g * 8];
      pfl[i] = *(const bf16x8*)&Pwl[wid][(i * 16 + l15) * PST + g * 8];
    }
    #pragma unroll
    for (int ctc = 0; ctc < 4; ++ctc) {
      #pragma unroll
      for (int st = 0; st < 4; ++st) {
        acc[ctc][st] = __builtin_amdgcn_mfma_f32_16x16x32_bf16(vfh[ctc], pfh[st], acc[ctc][st], 0, 0, 0);
        acc[ctc][st] = __builtin_amdgcn_mfma_f32_16x16x32_bf16(vfh[ctc], pfl[st], acc[ctc][st], 0, 0, 0);
        acc[ctc][st] = __builtin_amdgcn_mfma_f32_16x16x32_bf16(vfl[ctc], pfh[st], acc[ctc][st], 0, 0, 0);
      }
    }

    // ---- write-late staging of next tile
    if (more) {
      int nb = cur ^ 1;
      bf16x8 h8, l8;
      cvt8(ka, kb4, h8, l8);
      *(bf16x8*)&KhL[nb][sr * KST + sc] = h8;
      *(bf16x8*)&KlL[nb][sr * KST + sc] = l8;
      cvt8(va, vb4, h8, l8);
      #pragma unroll
      for (int j = 0; j < 8; ++j) {
        VhL[nb][(sc + j) * VST + sr] = h8[j];
        VlL[nb][(sc + j) * VST + sr] = l8[j];
      }
    }
    cur ^= 1;
  }

  // ---- LN partial sums: lane holds O^T[c = ctc*16+4g+r][s = st*16+l15]
  #pragma unroll
  for (int ctc = 0; ctc < 4; ++ctc) {
    #pragma unroll
    for (int r = 0; r < 4; ++r) {
      float s1 = 0.f, s2 = 0.f;
      #pragma unroll
      for (int st = 0; st < 4; ++st) { float v = acc[ctc][st][r]; s1 += v; s2 += v * v; }
      #pragma unroll
      for (int m = 1; m <= 8; m <<= 1) {
        s1 += __shfl_xor(s1, m, 64);
        s2 += __shfl_xor(s2, m, 64);
      }
      if (l15 == 0) {
        int c = ctc * 16 + 4 * g + r;
        red1[wid * 64 + c] = s1;
        red2[wid * 64 + c] = s2;
      }
    }
  }
  __syncthreads();
  if (tid < 64) {
    float a1 = red1[tid] + red1[64 + tid] + red1[128 + tid] + red1[192 + tid];
    float a2 = red2[tid] + red2[64 + tid] + red2[128 + tid] + red2[192 + tid];
    atomicAdd(&stats[tid], a1);
    atomicAdd(&stats[64 + tid], a2);
  }

  // ---- store pre-LN to ob[n][v][s][c] (reg 0..3 = consecutive c -> float4)
  float* obp = ob + base;
  #pragma unroll
  for (int st = 0; st < 4; ++st)
    #pragma unroll
    for (int ctc = 0; ctc < 4; ++ctc)
      *(f32x4*)&obp[(size_t)(band + st * 16 + l15) * 64 + ctc * 16 + 4 * g] = acc[ctc][st];
}

// ============================================================================
// Vector attention (R3, verified) — fallback for small-ws mode B
// ============================================================================
__global__ __launch_bounds__(256, 3)
void k_attn(const float* __restrict__ qb, const float* __restrict__ kb,
            const float* __restrict__ vb, float* __restrict__ stats,
            float* __restrict__ obuf, int modeA)
{
  __shared__ float kt[2][KVT * CC];
  __shared__ float vt[2][KVT * CC];
  __shared__ float red1[256], red2[256];
  const int tid = threadIdx.x;
  const int bid = blockIdx.x;
  const size_t base = (size_t)bid * (TT * CC);
  float q[CC];
  {
    const float4* qp = (const float4*)(qb + base + (size_t)tid * CC);
    #pragma unroll
    for (int i = 0; i < 16; ++i) {
      float4 f = qp[i];
      q[i * 4 + 0] = f.x; q[i * 4 + 1] = f.y; q[i * 4 + 2] = f.z; q[i * 4 + 3] = f.w;
    }
  }
  float out[CC];
  #pragma unroll
  for (int c = 0; c < CC; ++c) out[c] = 0.0f;
  {
    const float4* ks = (const float4*)(kb + base);
    const float4* vs = (const float4*)(vb + base);
    float4 a0 = ks[tid], a1 = ks[256 + tid];
    float4 b0 = vs[tid], b1 = vs[256 + tid];
    float4* kd = (float4*)kt[0]; float4* vd = (float4*)vt[0];
    kd[tid] = a0; kd[256 + tid] = a1;
    vd[tid] = b0; vd[256 + tid] = b1;
  }
  int cur = 0;
  for (int tile = 0; tile < TT / KVT; ++tile) {
    __syncthreads();
    float4 ks0, ks1, vs0, vs1;
    const bool more = (tile < TT / KVT - 1);
    if (more) {
      const float4* ks = (const float4*)(kb + base + (size_t)(tile + 1) * KVT * CC);
      const float4* vs = (const float4*)(vb + base + (size_t)(tile + 1) * KVT * CC);
      ks0 = ks[tid]; ks1 = ks[256 + tid];
      vs0 = vs[tid]; vs1 = vs[256 + tid];
    }
    const float* ktc = kt[cur];
    const float* vtc = vt[cur];
    #pragma unroll 4
    for (int tt = 0; tt < KVT; ++tt) {
      const float4* kr = (const float4*)&ktc[tt * CC];
      const float4* vr = (const float4*)&vtc[tt * CC];
      float a0 = 0.f, a1 = 0.f, a2 = 0.f, a3 = 0.f;
      #pragma unroll
      for (int c4 = 0; c4 < 16; ++c4) {
        float4 kk = kr[c4];
        a0 = fmaf(q[c4 * 4 + 0], kk.x, a0);
        a1 = fmaf(q[c4 * 4 + 1], kk.y, a1);
        a2 = fmaf(q[c4 * 4 + 2], kk.z, a2);
        a3 = fmaf(q[c4 * 4 + 3], kk.w, a3);
      }
      float a = fast_tanh(((a0 + a1) + (a2 + a3)) * 0.125f);
      #pragma unroll
      for (int c4 = 0; c4 < 16; ++c4) {
        float4 vv = vr[c4];
        out[c4 * 4 + 0] = fmaf(a, vv.x, out[c4 * 4 + 0]);
        out[c4 * 4 + 1] = fmaf(a, vv.y, out[c4 * 4 + 1]);
        out[c4 * 4 + 2] = fmaf(a, vv.z, out[c4 * 4 + 2]);
        out[c4 * 4 + 3] = fmaf(a, vv.w, out[c4 * 4 + 3]);
      }
    }
    if (more) {
      float4* kd = (float4*)kt[cur ^ 1]; float4* vd = (float4*)vt[cur ^ 1];
      kd[tid] = ks0; kd[256 + tid] = ks1;
      vd[tid] = vs0; vd[256 + tid] = vs1;
    }
    cur ^= 1;
  }
  const int lane = tid & 63, wid = tid >> 6;
  #pragma unroll
  for (int c = 0; c < CC; ++c) {
    float v1 = out[c];
    float v2 = v1 * v1;
    #pragma unroll
    for (int m = 32; m >= 1; m >>= 1) {
      v1 += __shfl_xor(v1, m, 64);
      v2 += __shfl_xor(v2, m, 64);
    }
    if (lane == c) { red1[wid * 64 + c] = v1; red2[wid * 64 + c] = v2; }
  }
  __syncthreads();
  if (tid < 64) {
    float s1 = red1[tid] + red1[64 + tid] + red1[128 + tid] + red1[192 + tid];
    float s2 = red2[tid] + red2[64 + tid] + red2[128 + tid] + red2[192 + tid];
    atomicAdd(&stats[tid], s1);
    atomicAdd(&stats[64 + tid], s2);
  }
  if (modeA) {
    float4* op = (float4*)(obuf + base + (size_t)tid * CC);
    #pragma unroll
    for (int i = 0; i < 16; ++i)
      op[i] = make_float4(out[i * 4], out[i * 4 + 1], out[i * 4 + 2], out[i * 4 + 3]);
  } else {
    const int n = bid / VV, v = bid - n * VV;
    float* op = obuf + (size_t)n * CC * TT * VV + (size_t)tid * VV + v;
    #pragma unroll
    for (int c = 0; c < CC; ++c) op[(size_t)c * TT * VV] = out[c];
  }
}

// ============================================================================
// Epilogue (unchanged, verified)
// ============================================================================
__global__ void k2_stats(const float* __restrict__ stats,
                         const float* __restrict__ gamma,
                         const float* __restrict__ beta,
                         float* __restrict__ ss)
{
  int c = threadIdx.x;
  if (c < 64) {
    const float M = (float)(NN * TT * VV);
    float mean = stats[c] / M;
    float var = stats[64 + c] / M - mean * mean;
    float sc = gamma[c] * rsqrtf(var + 1e-5f);
    ss[c] = sc;
    ss[64 + c] = beta[c] - mean * sc;
  }
}

__global__ __launch_bounds__(256)
void k3_emit(const float* __restrict__ ob, const float* __restrict__ ss,
             float* __restrict__ out)
{
  __shared__ float tile[VV * 8 * 65];
  __shared__ float scl[64], sft[64];
  const int bid = blockIdx.x;
  const int n = bid >> 5, sb = bid & 31;
  const int tid = threadIdx.x;
  if (tid < 64) { scl[tid] = ss[tid]; sft[tid] = ss[64 + tid]; }
  for (int v = 0; v < VV; ++v) {
    const float2* src = (const float2*)(ob + (((size_t)(n * VV + v)) * TT + sb * 8) * CC);
    float2 f = src[tid];
    int e = tid * 2; int sL = e >> 6, c = e & 63;
    tile[(v * 8 + sL) * 65 + c] = f.x;
    tile[(v * 8 + sL) * 65 + c + 1] = f.y;
  }
  __syncthreads();
  float* outn = out + (size_t)n * CC * TT * VV + sb * 8 * VV;
  for (int e = tid; e < CC * 200; e += 256) {
    int c = e / 200, r = e - c * 200;
    int sL = r / 25, v = r - sL * 25;
    float val = tile[(v * 8 + sL) * 65 + c];
    outn[(size_t)c * TT * VV + sL * VV + v] = val * scl[c] + sft[c];
  }
}

__global__ void k3b_inplace(float* __restrict__ out, const float* __restrict__ ss) {
  __shared__ float scl[64], sft[64];
  if (threadIdx.x < 64) { scl[threadIdx.x] = ss[threadIdx.x]; sft[threadIdx.x] = ss[64 + threadIdx.x]; }
  __syncthreads();
  const size_t total = (size_t)NN * CC * TT * VV;
  size_t i = ((size_t)blockIdx.x * 256 + threadIdx.x) * 4;
  const size_t stride = (size_t)gridDim.x * 256 * 4;
  for (; i < total; i += stride) {
    float4 val = *(float4*)(out + i);
    int c = (int)((i / (TT * VV)) & 63);
    val.x = val.x * scl[c] + sft[c];
    val.y = val.y * scl[c] + sft[c];
    val.z = val.z * scl[c] + sft[c];
    val.w = val.w * scl[c] + sft[c];
    *(float4*)(out + i) = val;
  }
}

// ============================================================================
// Path C fallback: round-1 fused kernel (verbatim, known-correct)
// ============================================================================
__device__ __forceinline__ void proj_row(const float* xs, const float* Wl,
                                         const float* bl, float* dst) {
  for (int d4 = 0; d4 < 16; ++d4) {
    float4 r;
    #pragma unroll
    for (int j = 0; j < 4; ++j) {
      const int d = d4 * 4 + j;
      float acc = bl[d];
      #pragma unroll
      for (int c = 0; c < CC; ++c) acc += xs[c] * Wl[d * CC + c];
      ((float*)&r)[j] = acc;
    }
    *(float4*)&dst[d4 * 4] = r;
  }
}

__global__ __launch_bounds__(256)
void k1_attn(const float* __restrict__ x,
             const float* __restrict__ Wq, const float* __restrict__ bq,
             const float* __restrict__ Wk, const float* __restrict__ bk,
             const float* __restrict__ Wv, const float* __restrict__ bv,
             float* __restrict__ stats, float* __restrict__ outbuf, int to_ws)
{
  __shared__ float kl[TT * PAD];
  __shared__ float vl[TT * PAD];
  __shared__ float Wl[CC * CC];
  __shared__ float bl[CC];
  const int tid = threadIdx.x;
  const int bid = blockIdx.x;
  const int n = bid / VV, v = bid - n * VV;
  float xs[CC];
  {
    const float* xp = x + ((size_t)n * CC * TT + tid) * VV + v;
    #pragma unroll
    for (int c = 0; c < CC; ++c) xs[c] = xp[(size_t)c * TT * VV];
  }
  {
    const float4* Wg = (const float4*)Wq;
    float4* Wd = (float4*)Wl;
    #pragma unroll
    for (int j = 0; j < 4; ++j) Wd[j * 256 + tid] = Wg[j * 256 + tid];
    if (tid < CC) bl[tid] = bq[tid];
    __syncthreads();
    proj_row(xs, Wl, bl, &kl[tid * PAD]);
  }
  float q[CC];
  #pragma unroll
  for (int c4 = 0; c4 < 16; ++c4) {
    float4 t4 = *(const float4*)&kl[tid * PAD + c4 * 4];
    q[c4 * 4 + 0] = t4.x; q[c4 * 4 + 1] = t4.y;
    q[c4 * 4 + 2] = t4.z; q[c4 * 4 + 3] = t4.w;
  }
  __syncthreads();
  {
    const float4* Wg = (const float4*)Wk;
    float4* Wd = (float4*)Wl;
    #pragma unroll
    for (int j = 0; j < 4; ++j) Wd[j * 256 + tid] = Wg[j * 256 + tid];
    if (tid < CC) bl[tid] = bk[tid];
    __syncthreads();
    proj_row(xs, Wl, bl, &kl[tid * PAD]);
    __syncthreads();
  }
  {
    const float4* Wg = (const float4*)Wv;
    float4* Wd = (float4*)Wl;
    #pragma unroll
    for (int j = 0; j < 4; ++j) Wd[j * 256 + tid] = Wg[j * 256 + tid];
    if (tid < CC) bl[tid] = bv[tid];
    __syncthreads();
    proj_row(xs, Wl, bl, &vl[tid * PAD]);
    __syncthreads();
  }
  float out[CC];
  #pragma unroll
  for (int c = 0; c < CC; ++c) out[c] = 0.0f;
  for (int t = 0; t < TT; ++t) {
    const float4* kr = (const float4*)&kl[t * PAD];
    float acc = 0.0f;
    #pragma unroll
    for (int c4 = 0; c4 < 16; ++c4) {
      float4 kk = kr[c4];
      acc += q[c4 * 4 + 0] * kk.x + q[c4 * 4 + 1] * kk.y
           + q[c4 * 4 + 2] * kk.z + q[c4 * 4 + 3] * kk.w;
    }
    float a = fast_tanh(acc * 0.125f);
    const float4* vr = (const float4*)&vl[t * PAD];
    #pragma unroll
    for (int c4 = 0; c4 < 16; ++c4) {
      float4 vv = vr[c4];
      out[c4 * 4 + 0] += a * vv.x; out[c4 * 4 + 1] += a * vv.y;
      out[c4 * 4 + 2] += a * vv.z; out[c4 * 4 + 3] += a * vv.w;
    }
  }
  __syncthreads();
  float* out_lds = vl;
  #pragma unroll
  for (int c4 = 0; c4 < 16; ++c4) {
    *(float4*)&out_lds[tid * PAD + c4 * 4] =
        make_float4(out[c4 * 4 + 0], out[c4 * 4 + 1], out[c4 * 4 + 2], out[c4 * 4 + 3]);
  }
  __syncthreads();
  {
    const int c = tid & 63, g = tid >> 6;
    float s1 = 0.0f, s2 = 0.0f;
    for (int s = g * 64; s < g * 64 + 64; ++s) {
      float val = out_lds[s * PAD + c];
      s1 += val; s2 += val * val;
    }
    float* part = Wl;
    part[tid] = s1;
    part[256 + tid] = s2;
    __syncthreads();
    if (tid < 64) {
      float a1 = part[tid] + part[64 + tid] + part[128 + tid] + part[192 + tid];
      float a2 = part[256 + tid] + part[320 + tid] + part[384 + tid] + part[448 + tid];
      atomicAdd(&stats[tid], a1);
      atomicAdd(&stats[64 + tid], a2);
    }
  }
  if (to_ws) {
    float4* obp = (float4*)(outbuf + (size_t)(n * VV + v) * (TT * CC));
    #pragma unroll
    for (int k2 = 0; k2 < 16; ++k2) {
      int idx = k2 * 256 + tid;
      int s = idx >> 4, cq = idx & 15;
      obp[idx] = *(const float4*)&out_lds[s * PAD + cq * 4];
    }
  } else {
    float* obp = outbuf + (size_t)n * CC * TT * VV + v;
    for (int e = tid; e < TT * CC; e += 256) {
      int s = e >> 6, c = e & 63;
      obp[(size_t)c * TT * VV + (size_t)s * VV] = out_lds[s * PAD + c];
    }
  }
}

// ============================================================================

extern "C" void kernel_launch(void* const* d_in, const int* in_sizes, int n_in,
                              void* d_out, int out_size, void* d_ws, size_t ws_size,
                              hipStream_t stream) {
  (void)in_sizes; (void)n_in; (void)out_size;
  const float* x     = (const float*)d_in[0];
  const float* Wq    = (const float*)d_in[1];
  const float* bq    = (const float*)d_in[2];
  const float* Wk    = (const float*)d_in[3];
  const float* bk    = (const float*)d_in[4];
  const float* Wv    = (const float*)d_in[5];
  const float* bv    = (const float*)d_in[6];
  const float* gamma = (const float*)d_in[7];
  const float* beta  = (const float*)d_in[8];
  float* out = (float*)d_out;
  float* wsf = (float*)d_ws;

  float* stats = wsf;
  float* ss    = wsf + 128;
  const size_t per = (size_t)NN * VV * TT * CC;              // floats per buffer
  const size_t needB = 1024 + 3 * per * sizeof(float);       // ~157 MB
  const size_t needA = needB + per * sizeof(float);          // ~210 MB

  k0_zero<<<1, 128, 0, stream>>>(stats);

  if (ws_size >= needB) {
    float* qb = wsf + 256;
    float* kb = qb + per;
    float* vb = kb + per;
    const bool A = ws_size >= needA;
    float* ob = vb + per;
    k_proj<<<NN * 25, 256, 0, stream>>>(x, Wq, bq, Wk, bk, Wv, bv, qb, kb, vb);
    if (A) {
      k_attn_mfma<<<NN * VV, 256, 0, stream>>>(qb, kb, vb, stats, ob);
      k2_stats<<<1, 64, 0, stream>>>(stats, gamma, beta, ss);
      k3_emit<<<NN * 32, 256, 0, stream>>>(ob, ss, out);
    } else {
      k_attn<<<NN * VV, 256, 0, stream>>>(qb, kb, vb, stats, out, 0);
      k2_stats<<<1, 64, 0, stream>>>(stats, gamma, beta, ss);
      k3b_inplace<<<2048, 256, 0, stream>>>(out, ss);
    }
  } else {
    float* ob = wsf + 256;
    const size_t needC = 1024 + per * sizeof(float);
    const bool useC = ws_size >= needC;
    k1_attn<<<NN * VV, 256, 0, stream>>>(x, Wq, bq, Wk, bk, Wv, bv,
                                         stats, useC ? ob : out, useC ? 1 : 0);
    k2_stats<<<1, 64, 0, stream>>>(stats, gamma, beta, ss);
    if (useC) k3_emit<<<NN * 32, 256, 0, stream>>>(ob, ss, out);
    else      k3b_inplace<<<2048, 256, 0, stream>>>(out, ss);
  }
}

// Round 5
// 279.466 us; speedup vs baseline: 5.9260x; 2.0605x over previous
//
#include <hip/hip_runtime.h>
#include <hip/hip_bf16.h>
#include <math.h>

#define NN 32
#define CC 64
#define TT 256
#define VV 25
#define PAD 68     // old fused-path LDS stride
#define RS (VV * CC)          // 1600: row stride (floats) of [n][t][v][c] layout
#define PERN (TT * VV * CC)   // 409600 floats per n

// MFMA attention LDS strides (shorts); all multiples of 8 => 16B-aligned b128
#define KST 72
#define VST 40
#define PST 40
// k_proj LDS strides
#define XST 72     // shorts, X staging
#define FST 68     // floats, store-transpose buffer

typedef __attribute__((ext_vector_type(8))) short bf16x8;
typedef __attribute__((ext_vector_type(4))) float f32x4;

__device__ __forceinline__ float fast_tanh(float x) {
  float ax = fabsf(x);
  float e = __expf(-2.0f * ax);
  float r = 1.0f - 2.0f * e / (1.0f + e);
  return copysignf(r, x);
}
__device__ __forceinline__ unsigned short f2bf(float f) {   // RTN-even
  unsigned u = __float_as_uint(f);
  u += 0x7fff + ((u >> 16) & 1u);
  return (unsigned short)(u >> 16);
}
__device__ __forceinline__ float bf2f(unsigned short h) {
  return __uint_as_float(((unsigned)h) << 16);
}
__device__ __forceinline__ void cvt8(float4 a, float4 b, bf16x8& h8, bf16x8& l8) {
  unsigned short h;
  h = f2bf(a.x); h8[0] = (short)h; l8[0] = (short)f2bf(a.x - bf2f(h));
  h = f2bf(a.y); h8[1] = (short)h; l8[1] = (short)f2bf(a.y - bf2f(h));
  h = f2bf(a.z); h8[2] = (short)h; l8[2] = (short)f2bf(a.z - bf2f(h));
  h = f2bf(a.w); h8[3] = (short)h; l8[3] = (short)f2bf(a.w - bf2f(h));
  h = f2bf(b.x); h8[4] = (short)h; l8[4] = (short)f2bf(b.x - bf2f(h));
  h = f2bf(b.y); h8[5] = (short)h; l8[5] = (short)f2bf(b.y - bf2f(h));
  h = f2bf(b.z); h8[6] = (short)h; l8[6] = (short)f2bf(b.z - bf2f(h));
  h = f2bf(b.w); h8[7] = (short)h; l8[7] = (short)f2bf(b.w - bf2f(h));
}

__global__ void k0_zero(float* __restrict__ p) { p[threadIdx.x] = 0.0f; }

// ============================================================================
// k_wsplit: one-time W -> bf16 hi/lo (A-layout rows = [Wq|Wk|Wv]), bias concat,
// stats zero. 1 block x 256 threads.
// ============================================================================
__global__ void k_wsplit(const float* __restrict__ Wq, const float* __restrict__ Wk,
                         const float* __restrict__ Wv, const float* __restrict__ bq,
                         const float* __restrict__ bk, const float* __restrict__ bv,
                         unsigned short* __restrict__ wh, unsigned short* __restrict__ wl,
                         float* __restrict__ bcat, float* __restrict__ stats)
{
  const int tid = threadIdx.x;
  if (tid < 128) stats[tid] = 0.0f;
  for (int i = 0; i < 48; ++i) {
    int idx = i * 256 + tid;               // < 12288 = 192*64
    int r = idx >> 6, c = idx & 63;
    int m = r >> 6, ch = r & 63;
    const float* W = (m == 0) ? Wq : (m == 1) ? Wk : Wv;
    float w = W[ch * 64 + c];
    unsigned short h = f2bf(w);
    wh[idx] = h;
    wl[idx] = f2bf(w - bf2f(h));
  }
  if (tid < 192) {
    int m = tid >> 6, ch = tid & 63;
    const float* B = (m == 0) ? bq : (m == 1) ? bk : bv;
    bcat[tid] = B[ch];
  }
}

// ============================================================================
// k_proj_mfma: GEMM [192][64] x [64][128tv] per block; 1600 blocks.
// Output layout [n][t][v][c] (tv-contiguous rows) -> fully coalesced stores.
// ============================================================================
__global__ __launch_bounds__(256, 2)
void k_proj_mfma(const float* __restrict__ x,
                 const unsigned short* __restrict__ wh,
                 const unsigned short* __restrict__ wl,
                 const float* __restrict__ bcat,
                 float* __restrict__ qb, float* __restrict__ kb,
                 float* __restrict__ vb)
{
  __shared__ short Xbuf[2 * 128 * XST];    // hi | lo ; 36,864 B (reused as f32)
  short* Xh = Xbuf;
  short* Xl = Xbuf + 128 * XST;

  const int tid  = threadIdx.x;
  const int lane = tid & 63;
  const int wid  = tid >> 6;
  const int l15  = lane & 15;
  const int g    = lane >> 4;
  const int band = wid * 48;               // wave's 48 D-rows (3 row-tiles)

  const int n = blockIdx.x / 50;
  const int chunk = blockIdx.x - n * 50;   // 50 chunks of 128 tv
  const int tv0 = chunk * 128;
  const float* xn = x + (size_t)n * PERN + tv0;   // x[n][c][tv0+...]

  // ---- stage X: 64c x 128tv -> LDS bf16 hi/lo [tv][c]
  {
    const int cg  = tid >> 5;              // 0..7
    const int tvl = (tid & 31) * 4;        // tv quad
    #pragma unroll
    for (int r = 0; r < 2; ++r) {
      const int c0 = r * 32 + cg * 4;
      float4 r0 = *(const float4*)&xn[(size_t)(c0 + 0) * (TT * VV) + tvl];
      float4 r1 = *(const float4*)&xn[(size_t)(c0 + 1) * (TT * VV) + tvl];
      float4 r2 = *(const float4*)&xn[(size_t)(c0 + 2) * (TT * VV) + tvl];
      float4 r3 = *(const float4*)&xn[(size_t)(c0 + 3) * (TT * VV) + tvl];
      #pragma unroll
      for (int j = 0; j < 4; ++j) {        // 4x4 in-thread transpose
        float v0 = (&r0.x)[j], v1 = (&r1.x)[j], v2 = (&r2.x)[j], v3 = (&r3.x)[j];
        unsigned short h0 = f2bf(v0), h1 = f2bf(v1), h2 = f2bf(v2), h3 = f2bf(v3);
        *(short4*)&Xh[(tvl + j) * XST + c0] =
            make_short4((short)h0, (short)h1, (short)h2, (short)h3);
        *(short4*)&Xl[(tvl + j) * XST + c0] =
            make_short4((short)f2bf(v0 - bf2f(h0)), (short)f2bf(v1 - bf2f(h1)),
                        (short)f2bf(v2 - bf2f(h2)), (short)f2bf(v3 - bf2f(h3)));
      }
    }
  }

  // ---- W A-frags + bias from global (L2-resident), overlap with staging
  bf16x8 wfh[3][2], wfl[3][2];
  #pragma unroll
  for (int rt = 0; rt < 3; ++rt)
    #pragma unroll
    for (int ks = 0; ks < 2; ++ks) {
      size_t off = (size_t)(band + rt * 16 + l15) * 64 + ks * 32 + g * 8;
      wfh[rt][ks] = *(const bf16x8*)&wh[off];
      wfl[rt][ks] = *(const bf16x8*)&wl[off];
    }
  float bc[3][4];
  #pragma unroll
  for (int rt = 0; rt < 3; ++rt)
    #pragma unroll
    for (int r = 0; r < 4; ++r)
      bc[rt][r] = bcat[band + rt * 16 + 4 * g + r];

  __syncthreads();

  // ---- MFMA: D[192][128], wave covers rows band..band+47, all 128 cols
  f32x4 acc[3][8];
  #pragma unroll
  for (int rt = 0; rt < 3; ++rt)
    #pragma unroll
    for (int ct = 0; ct < 8; ++ct)
      acc[rt][ct] = (f32x4){0.f, 0.f, 0.f, 0.f};

  #pragma unroll
  for (int ct = 0; ct < 8; ++ct) {
    bf16x8 xh[2], xl[2];
    #pragma unroll
    for (int ks = 0; ks < 2; ++ks) {
      xh[ks] = *(const bf16x8*)&Xh[(ct * 16 + l15) * XST + ks * 32 + g * 8];
      xl[ks] = *(const bf16x8*)&Xl[(ct * 16 + l15) * XST + ks * 32 + g * 8];
    }
    #pragma unroll
    for (int rt = 0; rt < 3; ++rt)
      #pragma unroll
      for (int ks = 0; ks < 2; ++ks) {
        acc[rt][ct] = __builtin_amdgcn_mfma_f32_16x16x32_bf16(wfh[rt][ks], xh[ks], acc[rt][ct], 0, 0, 0);
        acc[rt][ct] = __builtin_amdgcn_mfma_f32_16x16x32_bf16(wfh[rt][ks], xl[ks], acc[rt][ct], 0, 0, 0);
        acc[rt][ct] = __builtin_amdgcn_mfma_f32_16x16x32_bf16(wfl[rt][ks], xh[ks], acc[rt][ct], 0, 0, 0);
      }
  }

  // ---- bias
  #pragma unroll
  for (int rt = 0; rt < 3; ++rt)
    #pragma unroll
    for (int ct = 0; ct < 8; ++ct)
      #pragma unroll
      for (int r = 0; r < 4; ++r)
        acc[rt][ct][r] += bc[rt][r];

  // ---- store: per matrix m, transpose D-rows [m*64,m*64+64) through LDS,
  //      then fully-coalesced float4 stores to the contiguous 32KB chunk.
  float* Fbuf = (float*)Xbuf;              // 128 x FST floats = 34,816 B
  #pragma unroll
  for (int m = 0; m < 3; ++m) {
    __syncthreads();                       // prior reads of Xbuf/Fbuf done
    #pragma unroll
    for (int rt = 0; rt < 3; ++rt) {
      int grow = band + rt * 16;
      if ((grow >> 6) == m) {
        int ch = (grow & 63) + 4 * g;
        #pragma unroll
        for (int ct = 0; ct < 8; ++ct)
          *(f32x4*)&Fbuf[(ct * 16 + l15) * FST + ch] = acc[rt][ct];
      }
    }
    __syncthreads();
    float* gd = (m == 0 ? qb : m == 1 ? kb : vb) + (size_t)n * PERN + (size_t)tv0 * CC;
    #pragma unroll
    for (int i = 0; i < 8; ++i) {
      int e = i * 256 + tid;               // 2048 float4s = 8192 floats
      int tv = e >> 4, c4 = (e & 15) * 4;
      *(float4*)&gd[(size_t)e * 4] = *(const float4*)&Fbuf[tv * FST + c4];
    }
  }
}

// ============================================================================
// MFMA attention (R4, verified) — only change: [n][t][v][c] addressing (RS=1600)
// ============================================================================
__global__ __launch_bounds__(256, 2)
void k_attn_mfma(const float* __restrict__ qb, const float* __restrict__ kb,
                 const float* __restrict__ vb, float* __restrict__ stats,
                 float* __restrict__ ob)
{
  __shared__ short KhL[2][32 * KST], KlL[2][32 * KST];
  __shared__ short VhL[2][64 * VST], VlL[2][64 * VST];
  __shared__ short Pwh[4][64 * PST], Pwl[4][64 * PST];
  __shared__ float red1[256], red2[256];

  const int tid  = threadIdx.x;
  const int lane = tid & 63;
  const int wid  = tid >> 6;
  const int l15  = lane & 15;
  const int g    = lane >> 4;
  const int band = wid * 64;
  const int bid  = blockIdx.x;
  const int n = bid / VV, v = bid - n * VV;
  const size_t base = (size_t)n * PERN + (size_t)v * CC;   // row stride RS

  const int sr = tid >> 3;
  const int sc = (tid & 7) * 8;

  bf16x8 qh[4][2], ql[4][2];
  #pragma unroll
  for (int rt = 0; rt < 4; ++rt) {
    #pragma unroll
    for (int ks = 0; ks < 2; ++ks) {
      const float* p = qb + base + (size_t)(band + rt * 16 + l15) * RS + ks * 32 + g * 8;
      cvt8(*(const float4*)p, *(const float4*)(p + 4), qh[rt][ks], ql[rt][ks]);
    }
  }

  f32x4 acc[4][4];
  #pragma unroll
  for (int i = 0; i < 4; ++i)
    #pragma unroll
    for (int j = 0; j < 4; ++j)
      acc[i][j] = (f32x4){0.f, 0.f, 0.f, 0.f};

  {
    const float* kp = kb + base + (size_t)sr * RS + sc;
    const float* vp = vb + base + (size_t)sr * RS + sc;
    float4 ka = *(const float4*)kp, kb4 = *(const float4*)(kp + 4);
    float4 va = *(const float4*)vp, vb4 = *(const float4*)(vp + 4);
    bf16x8 h8, l8;
    cvt8(ka, kb4, h8, l8);
    *(bf16x8*)&KhL[0][sr * KST + sc] = h8;
    *(bf16x8*)&KlL[0][sr * KST + sc] = l8;
    cvt8(va, vb4, h8, l8);
    #pragma unroll
    for (int j = 0; j < 8; ++j) {
      VhL[0][(sc + j) * VST + sr] = h8[j];
      VlL[0][(sc + j) * VST + sr] = l8[j];
    }
  }

  int cur = 0;
  for (int tl = 0; tl < 8; ++tl) {
    __syncthreads();
    const bool more = (tl < 7);
    float4 ka, kb4, va, vb4;
    if (more) {
      const float* kp = kb + base + (size_t)((tl + 1) * 32 + sr) * RS + sc;
      const float* vp = vb + base + (size_t)((tl + 1) * 32 + sr) * RS + sc;
      ka = *(const float4*)kp; kb4 = *(const float4*)(kp + 4);
      va = *(const float4*)vp; vb4 = *(const float4*)(vp + 4);
    }

    bf16x8 kfh[2][2], kfl[2][2];
    #pragma unroll
    for (int ct = 0; ct < 2; ++ct)
      #pragma unroll
      for (int ks = 0; ks < 2; ++ks) {
        kfh[ct][ks] = *(const bf16x8*)&KhL[cur][(ct * 16 + l15) * KST + ks * 32 + g * 8];
        kfl[ct][ks] = *(const bf16x8*)&KlL[cur][(ct * 16 + l15) * KST + ks * 32 + g * 8];
      }
    #pragma unroll
    for (int rt = 0; rt < 4; ++rt) {
      #pragma unroll
      for (int ct = 0; ct < 2; ++ct) {
        f32x4 s = (f32x4){0.f, 0.f, 0.f, 0.f};
        #pragma unroll
        for (int ks = 0; ks < 2; ++ks) {
          s = __builtin_amdgcn_mfma_f32_16x16x32_bf16(qh[rt][ks], kfh[ct][ks], s, 0, 0, 0);
          s = __builtin_amdgcn_mfma_f32_16x16x32_bf16(qh[rt][ks], kfl[ct][ks], s, 0, 0, 0);
          s = __builtin_amdgcn_mfma_f32_16x16x32_bf16(ql[rt][ks], kfh[ct][ks], s, 0, 0, 0);
        }
        #pragma unroll
        for (int r = 0; r < 4; ++r) {
          float p = fast_tanh(s[r] * 0.125f);
          unsigned short h = f2bf(p);
          int row = rt * 16 + 4 * g + r;
          Pwh[wid][row * PST + ct * 16 + l15] = (short)h;
          Pwl[wid][row * PST + ct * 16 + l15] = (short)f2bf(p - bf2f(h));
        }
      }
    }

    bf16x8 vfh[4], vfl[4], pfh[4], pfl[4];
    #pragma unroll
    for (int i = 0; i < 4; ++i) {
      vfh[i] = *(const bf16x8*)&VhL[cur][(i * 16 + l15) * VST + g * 8];
      vfl[i] = *(const bf16x8*)&VlL[cur][(i * 16 + l15) * VST + g * 8];
      pfh[i] = *(const bf16x8*)&Pwh[wid][(i * 16 + l15) * PST + g * 8];
      pfl[i] = *(const bf16x8*)&Pwl[wid][(i * 16 + l15) * PST + g * 8];
    }
    #pragma unroll
    for (int ctc = 0; ctc < 4; ++ctc) {
      #pragma unroll
      for (int st = 0; st < 4; ++st) {
        acc[ctc][st] = __builtin_amdgcn_mfma_f32_16x16x32_bf16(vfh[ctc], pfh[st], acc[ctc][st], 0, 0, 0);
        acc[ctc][st] = __builtin_amdgcn_mfma_f32_16x16x32_bf16(vfh[ctc], pfl[st], acc[ctc][st], 0, 0, 0);
        acc[ctc][st] = __builtin_amdgcn_mfma_f32_16x16x32_bf16(vfl[ctc], pfh[st], acc[ctc][st], 0, 0, 0);
      }
    }

    if (more) {
      int nb = cur ^ 1;
      bf16x8 h8, l8;
      cvt8(ka, kb4, h8, l8);
      *(bf16x8*)&KhL[nb][sr * KST + sc] = h8;
      *(bf16x8*)&KlL[nb][sr * KST + sc] = l8;
      cvt8(va, vb4, h8, l8);
      #pragma unroll
      for (int j = 0; j < 8; ++j) {
        VhL[nb][(sc + j) * VST + sr] = h8[j];
        VlL[nb][(sc + j) * VST + sr] = l8[j];
      }
    }
    cur ^= 1;
  }

  #pragma unroll
  for (int ctc = 0; ctc < 4; ++ctc) {
    #pragma unroll
    for (int r = 0; r < 4; ++r) {
      float s1 = 0.f, s2 = 0.f;
      #pragma unroll
      for (int st = 0; st < 4; ++st) { float vv = acc[ctc][st][r]; s1 += vv; s2 += vv * vv; }
      #pragma unroll
      for (int m = 1; m <= 8; m <<= 1) {
        s1 += __shfl_xor(s1, m, 64);
        s2 += __shfl_xor(s2, m, 64);
      }
      if (l15 == 0) {
        int c = ctc * 16 + 4 * g + r;
        red1[wid * 64 + c] = s1;
        red2[wid * 64 + c] = s2;
      }
    }
  }
  __syncthreads();
  if (tid < 64) {
    float a1 = red1[tid] + red1[64 + tid] + red1[128 + tid] + red1[192 + tid];
    float a2 = red2[tid] + red2[64 + tid] + red2[128 + tid] + red2[192 + tid];
    atomicAdd(&stats[tid], a1);
    atomicAdd(&stats[64 + tid], a2);
  }

  float* obp = ob + base;
  #pragma unroll
  for (int st = 0; st < 4; ++st)
    #pragma unroll
    for (int ctc = 0; ctc < 4; ++ctc)
      *(f32x4*)&obp[(size_t)(band + st * 16 + l15) * RS + ctc * 16 + 4 * g] = acc[ctc][st];
}

// ============================================================================
// Epilogue
// ============================================================================
__global__ void k2_stats(const float* __restrict__ stats,
                         const float* __restrict__ gamma,
                         const float* __restrict__ beta,
                         float* __restrict__ ss)
{
  int c = threadIdx.x;
  if (c < 64) {
    const float M = (float)(NN * TT * VV);
    float mean = stats[c] / M;
    float var = stats[64 + c] / M - mean * mean;
    float sc = gamma[c] * rsqrtf(var + 1e-5f);
    ss[c] = sc;
    ss[64 + c] = beta[c] - mean * sc;
  }
}

// ob[n][t][v][c] -> out[n][c][t][v] with LN; block = (n, 8-t band)
__global__ __launch_bounds__(256)
void k3_emit(const float* __restrict__ ob, const float* __restrict__ ss,
             float* __restrict__ out)
{
  __shared__ float tile[VV * 8 * 65];     // [v][tL][c], c-row padded
  __shared__ float scl[64], sft[64];
  const int bid = blockIdx.x;
  const int n = bid >> 5, sb = bid & 31;
  const int tid = threadIdx.x;
  if (tid < 64) { scl[tid] = ss[tid]; sft[tid] = ss[64 + tid]; }
  const float* src = ob + (size_t)n * PERN + (size_t)sb * 8 * RS;  // 12800 floats contig
  #pragma unroll
  for (int i = 0; i < 25; ++i) {
    int e2 = i * 512 + tid * 2;
    float2 f = *(const float2*)&src[e2];
    int c = e2 & 63;
    int r = e2 >> 6;                      // 0..199 = tL*25 + v
    int tL = r / 25, vv2 = r - tL * 25;
    tile[(vv2 * 8 + tL) * 65 + c] = f.x;
    tile[(vv2 * 8 + tL) * 65 + c + 1] = f.y;
  }
  __syncthreads();
  float* outn = out + (size_t)n * CC * TT * VV + sb * 8 * VV;
  for (int e = tid; e < CC * 200; e += 256) {
    int c = e / 200, r = e - c * 200;
    int tL = r / 25, v = r - tL * 25;
    float val = tile[(v * 8 + tL) * 65 + c];
    outn[(size_t)c * TT * VV + tL * VV + v] = val * scl[c] + sft[c];
  }
}

__global__ void k3b_inplace(float* __restrict__ out, const float* __restrict__ ss) {
  __shared__ float scl[64], sft[64];
  if (threadIdx.x < 64) { scl[threadIdx.x] = ss[threadIdx.x]; sft[threadIdx.x] = ss[64 + threadIdx.x]; }
  __syncthreads();
  const size_t total = (size_t)NN * CC * TT * VV;
  size_t i = ((size_t)blockIdx.x * 256 + threadIdx.x) * 4;
  const size_t stride = (size_t)gridDim.x * 256 * 4;
  for (; i < total; i += stride) {
    float4 val = *(float4*)(out + i);
    int c = (int)((i / (TT * VV)) & 63);
    val.x = val.x * scl[c] + sft[c];
    val.y = val.y * scl[c] + sft[c];
    val.z = val.z * scl[c] + sft[c];
    val.w = val.w * scl[c] + sft[c];
    *(float4*)(out + i) = val;
  }
}

// ============================================================================
// Path C fallback: round-1 fused kernel (verbatim, known-correct)
// ============================================================================
__device__ __forceinline__ void proj_row(const float* xs, const float* Wl,
                                         const float* bl, float* dst) {
  for (int d4 = 0; d4 < 16; ++d4) {
    float4 r;
    #pragma unroll
    for (int j = 0; j < 4; ++j) {
      const int d = d4 * 4 + j;
      float acc = bl[d];
      #pragma unroll
      for (int c = 0; c < CC; ++c) acc += xs[c] * Wl[d * CC + c];
      ((float*)&r)[j] = acc;
    }
    *(float4*)&dst[d4 * 4] = r;
  }
}

__global__ __launch_bounds__(256)
void k1_attn(const float* __restrict__ x,
             const float* __restrict__ Wq, const float* __restrict__ bq,
             const float* __restrict__ Wk, const float* __restrict__ bk,
             const float* __restrict__ Wv, const float* __restrict__ bv,
             float* __restrict__ stats, float* __restrict__ outbuf)
{
  __shared__ float kl[TT * PAD];
  __shared__ float vl[TT * PAD];
  __shared__ float Wl[CC * CC];
  __shared__ float bl[CC];
  const int tid = threadIdx.x;
  const int bid = blockIdx.x;
  const int n = bid / VV, v = bid - n * VV;
  float xs[CC];
  {
    const float* xp = x + ((size_t)n * CC * TT + tid) * VV + v;
    #pragma unroll
    for (int c = 0; c < CC; ++c) xs[c] = xp[(size_t)c * TT * VV];
  }
  {
    const float4* Wg = (const float4*)Wq;
    float4* Wd = (float4*)Wl;
    #pragma unroll
    for (int j = 0; j < 4; ++j) Wd[j * 256 + tid] = Wg[j * 256 + tid];
    if (tid < CC) bl[tid] = bq[tid];
    __syncthreads();
    proj_row(xs, Wl, bl, &kl[tid * PAD]);
  }
  float q[CC];
  #pragma unroll
  for (int c4 = 0; c4 < 16; ++c4) {
    float4 t4 = *(const float4*)&kl[tid * PAD + c4 * 4];
    q[c4 * 4 + 0] = t4.x; q[c4 * 4 + 1] = t4.y;
    q[c4 * 4 + 2] = t4.z; q[c4 * 4 + 3] = t4.w;
  }
  __syncthreads();
  {
    const float4* Wg = (const float4*)Wk;
    float4* Wd = (float4*)Wl;
    #pragma unroll
    for (int j = 0; j < 4; ++j) Wd[j * 256 + tid] = Wg[j * 256 + tid];
    if (tid < CC) bl[tid] = bk[tid];
    __syncthreads();
    proj_row(xs, Wl, bl, &kl[tid * PAD]);
    __syncthreads();
  }
  {
    const float4* Wg = (const float4*)Wv;
    float4* Wd = (float4*)Wl;
    #pragma unroll
    for (int j = 0; j < 4; ++j) Wd[j * 256 + tid] = Wg[j * 256 + tid];
    if (tid < CC) bl[tid] = bv[tid];
    __syncthreads();
    proj_row(xs, Wl, bl, &vl[tid * PAD]);
    __syncthreads();
  }
  float out[CC];
  #pragma unroll
  for (int c = 0; c < CC; ++c) out[c] = 0.0f;
  for (int t = 0; t < TT; ++t) {
    const float4* kr = (const float4*)&kl[t * PAD];
    float acc = 0.0f;
    #pragma unroll
    for (int c4 = 0; c4 < 16; ++c4) {
      float4 kk = kr[c4];
      acc += q[c4 * 4 + 0] * kk.x + q[c4 * 4 + 1] * kk.y
           + q[c4 * 4 + 2] * kk.z + q[c4 * 4 + 3] * kk.w;
    }
    float a = fast_tanh(acc * 0.125f);
    const float4* vr = (const float4*)&vl[t * PAD];
    #pragma unroll
    for (int c4 = 0; c4 < 16; ++c4) {
      float4 vv = vr[c4];
      out[c4 * 4 + 0] += a * vv.x; out[c4 * 4 + 1] += a * vv.y;
      out[c4 * 4 + 2] += a * vv.z; out[c4 * 4 + 3] += a * vv.w;
    }
  }
  __syncthreads();
  float* out_lds = vl;
  #pragma unroll
  for (int c4 = 0; c4 < 16; ++c4) {
    *(float4*)&out_lds[tid * PAD + c4 * 4] =
        make_float4(out[c4 * 4 + 0], out[c4 * 4 + 1], out[c4 * 4 + 2], out[c4 * 4 + 3]);
  }
  __syncthreads();
  {
    const int c = tid & 63, gg = tid >> 6;
    float s1 = 0.0f, s2 = 0.0f;
    for (int s = gg * 64; s < gg * 64 + 64; ++s) {
      float val = out_lds[s * PAD + c];
      s1 += val; s2 += val * val;
    }
    float* part = Wl;
    part[tid] = s1;
    part[256 + tid] = s2;
    __syncthreads();
    if (tid < 64) {
      float a1 = part[tid] + part[64 + tid] + part[128 + tid] + part[192 + tid];
      float a2 = part[256 + tid] + part[320 + tid] + part[384 + tid] + part[448 + tid];
      atomicAdd(&stats[tid], a1);
      atomicAdd(&stats[64 + tid], a2);
    }
  }
  {
    float* obp = outbuf + (size_t)n * CC * TT * VV + v;
    for (int e = tid; e < TT * CC; e += 256) {
      int s = e >> 6, c = e & 63;
      obp[(size_t)c * TT * VV + (size_t)s * VV] = out_lds[s * PAD + c];
    }
  }
}

// ============================================================================

extern "C" void kernel_launch(void* const* d_in, const int* in_sizes, int n_in,
                              void* d_out, int out_size, void* d_ws, size_t ws_size,
                              hipStream_t stream) {
  (void)in_sizes; (void)n_in; (void)out_size;
  const float* x     = (const float*)d_in[0];
  const float* Wq    = (const float*)d_in[1];
  const float* bq    = (const float*)d_in[2];
  const float* Wk    = (const float*)d_in[3];
  const float* bk    = (const float*)d_in[4];
  const float* Wv    = (const float*)d_in[5];
  const float* bv    = (const float*)d_in[6];
  const float* gamma = (const float*)d_in[7];
  const float* beta  = (const float*)d_in[8];
  float* out = (float*)d_out;
  float* wsf = (float*)d_ws;

  // ws map: [stats 128][ss 128][bcat 256][wh+wl 12288 floats worth][qb|kb|vb|ob]
  float* stats = wsf;
  float* ss    = wsf + 128;
  float* bcat  = wsf + 256;
  unsigned short* wh = (unsigned short*)(wsf + 512);
  unsigned short* wl = wh + 192 * 64;
  float* qb = wsf + 512 + 12288;               // wh+wl = 24576 ushorts = 12288 floats
  const size_t per = (size_t)NN * PERN;        // 13,107,200 floats each
  float* kb = qb + per;
  float* vb = kb + per;
  float* ob = vb + per;
  const size_t need = (512 + 12288 + 4 * per) * sizeof(float);

  if (ws_size >= need) {
    k_wsplit<<<1, 256, 0, stream>>>(Wq, Wk, Wv, bq, bk, bv, wh, wl, bcat, stats);
    k_proj_mfma<<<NN * 50, 256, 0, stream>>>(x, wh, wl, bcat, qb, kb, vb);
    k_attn_mfma<<<NN * VV, 256, 0, stream>>>(qb, kb, vb, stats, ob);
    k2_stats<<<1, 64, 0, stream>>>(stats, gamma, beta, ss);
    k3_emit<<<NN * 32, 256, 0, stream>>>(ob, ss, out);
  } else {
    k0_zero<<<1, 128, 0, stream>>>(stats);
    k1_attn<<<NN * VV, 256, 0, stream>>>(x, Wq, bq, Wk, bk, Wv, bv, stats, out);
    k2_stats<<<1, 64, 0, stream>>>(stats, gamma, beta, ss);
    k3b_inplace<<<2048, 256, 0, stream>>>(out, ss);
  }
}